// Round 1
// baseline (377.138 us; speedup 1.0000x reference)
//
#include <hip/hip_runtime.h>

// GaussianPooling: fm[512,256,256] f32, keypoints[4096,2] int (x,w-coord first),
// out[4096,512] f32. 5x5 gaussian (sigma=2), separable: k = gy(dy)*gx(dx)/s^2.
//
// Layout strategy: one block per keypoint, 256 threads, thread t -> channels
// {t, t+256}. Per (c,row) load the two aligned float4 covering the 5-wide
// window; 8-wide shifted weight vector wx handles sub-alignment r=(x-2)&3.
// All 20 loads per thread fully unrolled for MLP.

#define NC 512
#define NH 256
#define NW 256

__global__ __launch_bounds__(256) void gpool_kernel(
    const float* __restrict__ fm,
    const int* __restrict__ kp,
    float* __restrict__ out)
{
    const int n = blockIdx.x;
    const int t = threadIdx.x;

    int x = kp[2 * n + 0];
    int y = kp[2 * n + 1];
    x = min(max(x, 2), NW - 3);   // clip to [2, 253]
    y = min(max(y, 2), NH - 3);

    // separable gaussian, sigma=2: g = exp(-d^2/8), d in {-2..2}
    const float e1 = 0.8824969025845955f;  // exp(-1/8)
    const float e2 = 0.6065306597126334f;  // exp(-4/8)
    const float s  = 2.0f * (e1 + e2) + 1.0f;
    const float inv_s2 = 1.0f / (s * s);
    float g[5] = {e2, e1, 1.0f, e1, e2};
    float gy[5];
#pragma unroll
    for (int i = 0; i < 5; i++) gy[i] = g[i] * inv_s2;

    const int x0 = x - 2;
    const int r  = x0 & 3;        // sub-alignment within float4
    const int xa = x0 - r;        // aligned window start, in [0, 248]
    float wx[8];
#pragma unroll
    for (int i = 0; i < 8; i++)
        wx[i] = (i >= r && i < r + 5) ? g[i - r] : 0.0f;

    const int c0 = t;
    const int c1 = t + 256;
    const float* base0 = fm + ((size_t)c0 * NH + (y - 2)) * NW + xa;
    const float* base1 = fm + ((size_t)c1 * NH + (y - 2)) * NW + xa;

    float acc0 = 0.0f, acc1 = 0.0f;
#pragma unroll
    for (int dy = 0; dy < 5; dy++) {
        const float4* p0 = (const float4*)(base0 + dy * NW);
        const float4* p1 = (const float4*)(base1 + dy * NW);
        float4 a0 = p0[0];
        float4 b0 = p0[1];
        float4 a1 = p1[0];
        float4 b1 = p1[1];
        float rs0 = a0.x * wx[0] + a0.y * wx[1] + a0.z * wx[2] + a0.w * wx[3]
                  + b0.x * wx[4] + b0.y * wx[5] + b0.z * wx[6] + b0.w * wx[7];
        float rs1 = a1.x * wx[0] + a1.y * wx[1] + a1.z * wx[2] + a1.w * wx[3]
                  + b1.x * wx[4] + b1.y * wx[5] + b1.z * wx[6] + b1.w * wx[7];
        acc0 += gy[dy] * rs0;
        acc1 += gy[dy] * rs1;
    }

    out[(size_t)n * NC + c0] = acc0;
    out[(size_t)n * NC + c1] = acc1;
}

extern "C" void kernel_launch(void* const* d_in, const int* in_sizes, int n_in,
                              void* d_out, int out_size, void* d_ws, size_t ws_size,
                              hipStream_t stream)
{
    const float* fm  = (const float*)d_in[0];
    const int*   kp  = (const int*)d_in[1];
    float*       out = (float*)d_out;

    const int n_kp = in_sizes[1] / 2;   // 4096
    gpool_kernel<<<n_kp, 256, 0, stream>>>(fm, kp, out);
}

// Round 2
// 247.188 us; speedup vs baseline: 1.5257x; 1.5257x over previous
//
#include <hip/hip_runtime.h>

// GaussianPooling: fm[512,256,256] f32, keypoints[4096,2] int, out[4096,512] f32.
// 5x5 gaussian (sigma=2), separable: k = g(dy)*g(dx)/s^2.
//
// Round-2 strategy: the [C,H,W] layout makes gathers uncoalescable (channel
// stride 256 KB -> 64 distinct lines per wave load; R1 fetched 805 MB for a
// 128 MB compulsory input). Fix: transpose to [H,W,C] in d_ws (both sides
// coalesced), then gather reads 2 KB contiguous channel runs per patch
// position -> every fetched byte used. 460 MB total coalesced traffic.

#define NC 512
#define NH 256
#define NW 256
#define HW (NH * NW)

#define TDIM 32
#define TROWS 8

// ---------------- transpose: fm [NC][HW] -> ws [HW][NC] ----------------
__global__ __launch_bounds__(256) void transpose_kernel(
    const float* __restrict__ fm, float* __restrict__ ws)
{
    __shared__ float tile[TDIM][TDIM + 1];
    const int hw0 = blockIdx.x * TDIM;
    const int c0  = blockIdx.y * TDIM;
    const int tx  = threadIdx.x;   // 0..31
    const int ty  = threadIdx.y;   // 0..7

#pragma unroll
    for (int k = 0; k < TDIM; k += TROWS)
        tile[ty + k][tx] = fm[(size_t)(c0 + ty + k) * HW + hw0 + tx];

    __syncthreads();

#pragma unroll
    for (int k = 0; k < TDIM; k += TROWS)
        ws[(size_t)(hw0 + ty + k) * NC + c0 + tx] = tile[tx][ty + k];
}

// ---------------- gather on [H,W,C]: block = keypoint ----------------
__global__ __launch_bounds__(256) void gather_kernel(
    const float* __restrict__ ws, const int* __restrict__ kp,
    float* __restrict__ out)
{
    const int n = blockIdx.x;
    const int t = threadIdx.x;

    int x = kp[2 * n + 0];
    int y = kp[2 * n + 1];
    x = min(max(x, 2), NW - 3);
    y = min(max(y, 2), NH - 3);

    const float e1 = 0.8824969025845955f;  // exp(-1/8)
    const float e2 = 0.6065306597126334f;  // exp(-4/8)
    const float s  = 2.0f * (e1 + e2) + 1.0f;
    const float inv_s2 = 1.0f / (s * s);
    const float g[5] = {e2, e1, 1.0f, e1, e2};

    // float2 view: position p has 256 float2; thread t takes channels {2t,2t+1}
    const float2* base = (const float2*)ws
                       + ((size_t)(y - 2) * NW + (x - 2)) * (NC / 2) + t;

    float2 acc = {0.0f, 0.0f};
#pragma unroll
    for (int dy = 0; dy < 5; dy++) {
        const float wy = g[dy] * inv_s2;
#pragma unroll
        for (int dx = 0; dx < 5; dx++) {
            const float w = wy * g[dx];
            float2 v = base[((size_t)dy * NW + dx) * (NC / 2)];
            acc.x += w * v.x;
            acc.y += w * v.y;
        }
    }

    ((float2*)out)[(size_t)n * (NC / 2) + t] = acc;
}

// ---------------- fallback (round-1 direct kernel) ----------------
__global__ __launch_bounds__(256) void gpool_direct_kernel(
    const float* __restrict__ fm, const int* __restrict__ kp,
    float* __restrict__ out)
{
    const int n = blockIdx.x;
    const int t = threadIdx.x;

    int x = kp[2 * n + 0];
    int y = kp[2 * n + 1];
    x = min(max(x, 2), NW - 3);
    y = min(max(y, 2), NH - 3);

    const float e1 = 0.8824969025845955f;
    const float e2 = 0.6065306597126334f;
    const float s  = 2.0f * (e1 + e2) + 1.0f;
    const float inv_s2 = 1.0f / (s * s);
    float g[5] = {e2, e1, 1.0f, e1, e2};
    float gy[5];
#pragma unroll
    for (int i = 0; i < 5; i++) gy[i] = g[i] * inv_s2;

    const int x0 = x - 2;
    const int r  = x0 & 3;
    const int xa = x0 - r;
    float wx[8];
#pragma unroll
    for (int i = 0; i < 8; i++)
        wx[i] = (i >= r && i < r + 5) ? g[i - r] : 0.0f;

    const float* base0 = fm + ((size_t)t * NH + (y - 2)) * NW + xa;
    const float* base1 = fm + ((size_t)(t + 256) * NH + (y - 2)) * NW + xa;

    float acc0 = 0.0f, acc1 = 0.0f;
#pragma unroll
    for (int dy = 0; dy < 5; dy++) {
        const float4* p0 = (const float4*)(base0 + dy * NW);
        const float4* p1 = (const float4*)(base1 + dy * NW);
        float4 a0 = p0[0], b0 = p0[1], a1 = p1[0], b1 = p1[1];
        acc0 += gy[dy] * (a0.x * wx[0] + a0.y * wx[1] + a0.z * wx[2] + a0.w * wx[3]
                        + b0.x * wx[4] + b0.y * wx[5] + b0.z * wx[6] + b0.w * wx[7]);
        acc1 += gy[dy] * (a1.x * wx[0] + a1.y * wx[1] + a1.z * wx[2] + a1.w * wx[3]
                        + b1.x * wx[4] + b1.y * wx[5] + b1.z * wx[6] + b1.w * wx[7]);
    }

    out[(size_t)n * NC + t]       = acc0;
    out[(size_t)n * NC + t + 256] = acc1;
}

extern "C" void kernel_launch(void* const* d_in, const int* in_sizes, int n_in,
                              void* d_out, int out_size, void* d_ws, size_t ws_size,
                              hipStream_t stream)
{
    const float* fm  = (const float*)d_in[0];
    const int*   kp  = (const int*)d_in[1];
    float*       out = (float*)d_out;
    const int n_kp   = in_sizes[1] / 2;   // 4096

    const size_t need = (size_t)HW * NC * sizeof(float);   // 128 MB
    if (ws_size >= need) {
        float* ws = (float*)d_ws;
        dim3 tgrid(HW / TDIM, NC / TDIM);   // 2048 x 16
        dim3 tblk(TDIM, TROWS);             // 32 x 8 = 256
        transpose_kernel<<<tgrid, tblk, 0, stream>>>(fm, ws);
        gather_kernel<<<n_kp, NC / 2, 0, stream>>>(ws, kp, out);
    } else {
        gpool_direct_kernel<<<n_kp, 256, 0, stream>>>(fm, kp, out);
    }
}

// Round 4
// 219.032 us; speedup vs baseline: 1.7218x; 1.1285x over previous
//
#include <hip/hip_runtime.h>

// GaussianPooling: fm[512,256,256] f32, keypoints[4096,2] int, out[4096,512] f32.
// 5x5 gaussian sigma=2, separable: k = g(dy)*g(dx)/s^2.
//
// R4: R3 died on >64 KB static LDS (70,720 B vs 65,536 limit; compiles, launch
// aborts). Same plan with 8 y-octants: 36-row x 260-float plane slice =
// 37,440 B LDS, 4 blocks/CU. Block = (channel, octant): stage slice coalesced,
// compute bucketed keypoints from LDS (2x ds_read_b128 + 8-wide shifted dot
// per row; wave64 b128 floors at 8 clk so random-address conflicts are ~free),
// stage outT[c][n], then small 16 MB transpose.

#define NC  512
#define NH  256
#define NW  256
#define NKP 4096

#define OCT 8
#define SLICE_ROWS 36          // 32 + 2x2 halo
#define STR 260                // LDS row stride (floats): +4 keeps 16B align, rotates banks

// ws layout (bytes):
//   ints [0..7]                  cnt[8]
//   ints [16 .. 16+8*NKP)        packed lists, stride NKP u32 per octant
//   bytes [262144 .. +8MB)       outT [NC][NKP] floats
#define WS_LIST_OFF_I 16
#define WS_OUTT_OFF_B 262144

// ---------------- bucket: clip + pack + partition by y-octant ----------------
__global__ __launch_bounds__(256) void bucket_kernel(
    const int* __restrict__ kp, unsigned* __restrict__ ws_i, int n_kp)
{
    __shared__ unsigned llist[NKP];
    __shared__ int lcnt;
    const int q = blockIdx.x;
    const int t = threadIdx.x;
    if (t == 0) lcnt = 0;
    __syncthreads();

    for (int i = t; i < n_kp; i += 256) {
        int x = kp[2 * i + 0];
        int y = kp[2 * i + 1];
        x = min(max(x, 2), NW - 3);
        y = min(max(y, 2), NH - 3);
        if ((y >> 5) == q) {
            int pos = atomicAdd(&lcnt, 1);
            llist[pos] = (unsigned)i | ((unsigned)x << 12) | ((unsigned)y << 20);
        }
    }
    __syncthreads();
    const int c = lcnt;
    for (int i = t; i < c; i += 256)
        ws_i[WS_LIST_OFF_I + q * NKP + i] = llist[i];
    if (t == 0) ws_i[q] = (unsigned)c;
}

// ---------------- pool: block = (channel, y-octant), plane slice in LDS ----------------
__global__ __launch_bounds__(256) void pool_kernel(
    const float* __restrict__ fm, const unsigned* __restrict__ ws_i,
    float* __restrict__ outT)
{
    __shared__ float plane[SLICE_ROWS * STR];   // 37,440 B

    const int c = blockIdx.x;
    const int q = blockIdx.y;
    const int t = threadIdx.x;
    const int ybase = q * 32 - 2;

    // stage rows [ybase, ybase+35] clamped to [0,255]; fully coalesced float4
    const float4* src = (const float4*)(fm + ((size_t)c << 16));
#pragma unroll
    for (int it = 0; it < (SLICE_ROWS * 64) / 256; ++it) {
        const int i = t + it * 256;
        const int row = i >> 6;
        const int col4 = i & 63;
        const int gr = ybase + row;
        if ((unsigned)gr < 256u) {
            float4 v = src[(gr << 6) + col4];
            *(float4*)&plane[row * STR + (col4 << 2)] = v;
        }
    }
    __syncthreads();

    // gaussian weights
    const float e1 = 0.8824969025845955f;  // exp(-1/8)
    const float e2 = 0.6065306597126334f;  // exp(-4/8)
    const float s  = 2.0f * (e1 + e2) + 1.0f;
    const float inv_s2 = 1.0f / (s * s);
    const float g[5] = {e2, e1, 1.0f, e1, e2};
    float gy[5];
#pragma unroll
    for (int i = 0; i < 5; i++) gy[i] = g[i] * inv_s2;

    const int cnt = (int)ws_i[q];
    const unsigned* list = ws_i + WS_LIST_OFF_I + q * NKP;

    for (int e = t; e < cnt; e += 256) {
        const unsigned pk = list[e];
        const int n  = (int)(pk & 0xFFFu);
        const int xc = (int)((pk >> 12) & 0xFFu);
        const int yc = (int)((pk >> 20) & 0xFFu);

        const int x0 = xc - 2;
        const int r  = x0 & 3;
        const int xa = x0 - r;
        float wx[8];
#pragma unroll
        for (int i = 0; i < 8; i++)
            wx[i] = (i >= r && i < r + 5) ? g[i - r] : 0.0f;

        const int lr0 = yc - (q << 5);   // plane row of (yc-2): 0..31
        float acc = 0.0f;
#pragma unroll
        for (int dy = 0; dy < 5; dy++) {
            const float* rowp = &plane[(lr0 + dy) * STR + xa];
            float4 a = *(const float4*)rowp;
            float4 b = *(const float4*)(rowp + 4);
            acc += gy[dy] * (a.x * wx[0] + a.y * wx[1] + a.z * wx[2] + a.w * wx[3]
                           + b.x * wx[4] + b.y * wx[5] + b.z * wx[6] + b.w * wx[7]);
        }
        outT[((size_t)c << 12) + n] = acc;
    }
}

// ---------------- small transpose: outT [NC][NKP] -> out [NKP][NC] ----------------
__global__ __launch_bounds__(256) void outt_kernel(
    const float* __restrict__ outT, float* __restrict__ out)
{
    __shared__ float tile[32][33];
    const int n0 = blockIdx.x * 32;
    const int c0 = blockIdx.y * 32;
    const int tx = threadIdx.x;   // 0..31
    const int ty = threadIdx.y;   // 0..7

#pragma unroll
    for (int k = 0; k < 32; k += 8)
        tile[ty + k][tx] = outT[(size_t)(c0 + ty + k) * NKP + n0 + tx];
    __syncthreads();
#pragma unroll
    for (int k = 0; k < 32; k += 8)
        out[(size_t)(n0 + ty + k) * NC + c0 + tx] = tile[tx][ty + k];
}

// ---------------- fallback (round-1 direct kernel) ----------------
__global__ __launch_bounds__(256) void gpool_direct_kernel(
    const float* __restrict__ fm, const int* __restrict__ kp,
    float* __restrict__ out)
{
    const int n = blockIdx.x;
    const int t = threadIdx.x;

    int x = kp[2 * n + 0];
    int y = kp[2 * n + 1];
    x = min(max(x, 2), NW - 3);
    y = min(max(y, 2), NH - 3);

    const float e1 = 0.8824969025845955f;
    const float e2 = 0.6065306597126334f;
    const float s  = 2.0f * (e1 + e2) + 1.0f;
    const float inv_s2 = 1.0f / (s * s);
    float g[5] = {e2, e1, 1.0f, e1, e2};
    float gy[5];
#pragma unroll
    for (int i = 0; i < 5; i++) gy[i] = g[i] * inv_s2;

    const int x0 = x - 2;
    const int r  = x0 & 3;
    const int xa = x0 - r;
    float wx[8];
#pragma unroll
    for (int i = 0; i < 8; i++)
        wx[i] = (i >= r && i < r + 5) ? g[i - r] : 0.0f;

    const float* base0 = fm + ((size_t)t * NH + (y - 2)) * NW + xa;
    const float* base1 = fm + ((size_t)(t + 256) * NH + (y - 2)) * NW + xa;

    float acc0 = 0.0f, acc1 = 0.0f;
#pragma unroll
    for (int dy = 0; dy < 5; dy++) {
        const float4* p0 = (const float4*)(base0 + dy * NW);
        const float4* p1 = (const float4*)(base1 + dy * NW);
        float4 a0 = p0[0], b0 = p0[1], a1 = p1[0], b1 = p1[1];
        acc0 += gy[dy] * (a0.x * wx[0] + a0.y * wx[1] + a0.z * wx[2] + a0.w * wx[3]
                        + b0.x * wx[4] + b0.y * wx[5] + b0.z * wx[6] + b0.w * wx[7]);
        acc1 += gy[dy] * (a1.x * wx[0] + a1.y * wx[1] + a1.z * wx[2] + a1.w * wx[3]
                        + b1.x * wx[4] + b1.y * wx[5] + b1.z * wx[6] + b1.w * wx[7]);
    }

    out[(size_t)n * NC + t]       = acc0;
    out[(size_t)n * NC + t + 256] = acc1;
}

extern "C" void kernel_launch(void* const* d_in, const int* in_sizes, int n_in,
                              void* d_out, int out_size, void* d_ws, size_t ws_size,
                              hipStream_t stream)
{
    const float* fm  = (const float*)d_in[0];
    const int*   kp  = (const int*)d_in[1];
    float*       out = (float*)d_out;
    const int n_kp   = in_sizes[1] / 2;   // 4096

    const size_t need = WS_OUTT_OFF_B + (size_t)NC * NKP * sizeof(float);
    if (ws_size >= need && n_kp == NKP) {
        unsigned* ws_i = (unsigned*)d_ws;
        float* outT    = (float*)((char*)d_ws + WS_OUTT_OFF_B);

        bucket_kernel<<<OCT, 256, 0, stream>>>(kp, ws_i, n_kp);

        dim3 pgrid(NC, OCT);
        pool_kernel<<<pgrid, 256, 0, stream>>>(fm, ws_i, outT);

        dim3 tgrid(NKP / 32, NC / 32);
        dim3 tblk(32, 8);
        outt_kernel<<<tgrid, tblk, 0, stream>>>(outT, out);
    } else {
        gpool_direct_kernel<<<n_kp, 256, 0, stream>>>(fm, kp, out);
    }
}